// Round 4
// baseline (151.323 us; speedup 1.0000x reference)
//
#include <hip/hip_runtime.h>
#include <math.h>

#define Bn 512
#define Wn 512
#define En 512
#define EPSF 1e-5f

typedef float fx4 __attribute__((ext_vector_type(4)));

// ---- workspace layout (float offsets) ----
#define O_W1T    0                           // En*Wn = 262144
#define O_LIN    (O_W1T + En * Wn)           // + Bn*En
#define O_SCALE  (O_LIN + Bn * En)           // + En
#define O_SHIFT  (O_SCALE + En)              // + En
#define O_CTR    (O_SHIFT + En)              // + 1 (uint counter)

// W1 [E,W] -> W1T [W,E], LDS-tiled transpose. Also zeroes the block counter
// (deterministically, every call) before k_main runs.
__global__ void k_transpose(const float* __restrict__ w1, float* __restrict__ w1t,
                            unsigned int* __restrict__ ctr) {
    if (blockIdx.x == 0 && blockIdx.y == 0 && threadIdx.x == 0 && threadIdx.y == 0)
        *ctr = 0u;
    __shared__ float tile[32][33];
    int bx = blockIdx.x, by = blockIdx.y;     // bx: w-tile, by: e-tile
    int tx = threadIdx.x, ty = threadIdx.y;   // (32, 8)
#pragma unroll
    for (int j = 0; j < 32; j += 8)
        tile[ty + j][tx] = w1[(size_t)(by * 32 + ty + j) * Wn + bx * 32 + tx];
    __syncthreads();
#pragma unroll
    for (int j = 0; j < 32; j += 8)
        w1t[(size_t)(bx * 32 + ty + j) * En + by * 32 + tx] = tile[tx][ty + j];
}

// One block per b. 512 threads = 4 w-subchunks x 128 e4-lanes.
// lin[b][e] = sum_w x*W1T - x_last*sumW1 + b1   (sumW1 accumulated in-loop).
// The LAST block to finish (device-scope counter) computes the BN stats and
// writes scale/shift — saves a kernel launch. Fixed read order => deterministic.
__global__ __launch_bounds__(512) void k_main(const float* __restrict__ x,
                                              const float* __restrict__ w1t,
                                              const float* __restrict__ b1,
                                              const float* __restrict__ gamma,
                                              const float* __restrict__ beta,
                                              float* __restrict__ lin,
                                              float* __restrict__ scale,
                                              float* __restrict__ shift,
                                              unsigned int* __restrict__ ctr) {
    int b = blockIdx.x;
    int tid = threadIdx.x;
    int wsub = tid >> 7;      // 0..3
    int e4 = tid & 127;       // float4 index over e

    // hoist x_last load (used only in the wsub==0 tail) — latency hidden by loop
    fx4 xl = ((const fx4*)x)[((size_t)b * Wn + (Wn - 1)) * (En / 4) + e4];

    const fx4* xp = (const fx4*)x + ((size_t)b * Wn + (size_t)wsub * 128) * (En / 4) + e4;
    const fx4* wp = (const fx4*)w1t + (size_t)(wsub * 128) * (En / 4) + e4;

    fx4 acc = {0.f, 0.f, 0.f, 0.f};
    fx4 wsum = {0.f, 0.f, 0.f, 0.f};
#pragma unroll 8
    for (int w = 0; w < 128; ++w) {
        fx4 xv = __builtin_nontemporal_load(&xp[(size_t)w * (En / 4)]);
        fx4 wv = wp[(size_t)w * (En / 4)];
        acc += xv * wv;
        wsum += wv;
    }

    __shared__ fx4 lacc[4][128];
    __shared__ fx4 lws[4][128];
    lacc[wsub][e4] = acc;
    lws[wsub][e4] = wsum;
    __syncthreads();

    if (wsub == 0) {
        fx4 t = lacc[0][e4], u = lws[0][e4];
#pragma unroll
        for (int k = 1; k < 4; ++k) {
            t += lacc[k][e4];
            u += lws[k][e4];
        }
        fx4 bb = ((const fx4*)b1)[e4];
        fx4 r = t - xl * u + bb;
        ((fx4*)lin)[(size_t)b * (En / 4) + e4] = r;
    }

    // ---- last-block BN stats ----
    __shared__ int is_last;
    __syncthreads();          // lin stores issued by wsub==0 done program-order
    if (tid == 0) {
        __threadfence();      // release: make this block's lin visible device-wide
        unsigned int old = atomicAdd(ctr, 1u);
        is_last = (old == Bn - 1u) ? 1 : 0;
    }
    __syncthreads();
    if (is_last) {
        __threadfence();      // acquire: see all other blocks' lin
        int e = tid;          // 512 threads, one e each
        float s = 0.f, q = 0.f;
#pragma unroll 8
        for (int bb2 = 0; bb2 < Bn; ++bb2) {
            float v = lin[(size_t)bb2 * En + e];
            s += v;
            q += v * v;
        }
        float mean = s * (1.f / Bn);
        float var = q * (1.f / Bn) - mean * mean;
        float sc = gamma[e] * rsqrtf(var + EPSF);
        scale[e] = sc;
        shift[e] = beta[e] - mean * sc;
    }
}

// out[b] = sum_e (lin*scale + shift + seq_last) * W2[e] + b2
__global__ __launch_bounds__(128) void k_out(const float* __restrict__ lin,
                                             const float* __restrict__ x,
                                             const float* __restrict__ scale,
                                             const float* __restrict__ shift,
                                             const float* __restrict__ w2,
                                             const float* __restrict__ b2,
                                             float* __restrict__ out) {
    int b = blockIdx.x;
    int t = threadIdx.x;  // 128 -> float4 over e

    fx4 sc = ((const fx4*)scale)[t];
    fx4 sh = ((const fx4*)shift)[t];
    fx4 l  = ((const fx4*)lin)[(size_t)b * (En / 4) + t];
    fx4 xl = ((const fx4*)x)[((size_t)b * Wn + (Wn - 1)) * (En / 4) + t];
    fx4 wv = ((const fx4*)w2)[t];
    fx4 term = (l * sc + sh + xl) * wv;
    float v = term.x + term.y + term.z + term.w;
#pragma unroll
    for (int off = 32; off; off >>= 1) v += __shfl_down(v, off);
    __shared__ float red[2];
    int wid = t >> 6, lane = t & 63;
    if (lane == 0) red[wid] = v;
    __syncthreads();
    if (t == 0) out[b] = red[0] + red[1] + b2[0];
}

extern "C" void kernel_launch(void* const* d_in, const int* in_sizes, int n_in,
                              void* d_out, int out_size, void* d_ws, size_t ws_size,
                              hipStream_t stream) {
    const float* x     = (const float*)d_in[0];
    const float* w1    = (const float*)d_in[1];
    const float* b1    = (const float*)d_in[2];
    const float* gamma = (const float*)d_in[3];
    const float* beta  = (const float*)d_in[4];
    const float* w2    = (const float*)d_in[5];
    const float* b2    = (const float*)d_in[6];
    float* out = (float*)d_out;
    float* ws  = (float*)d_ws;

    float* w1t   = ws + O_W1T;
    float* lin   = ws + O_LIN;
    float* scale = ws + O_SCALE;
    float* shift = ws + O_SHIFT;
    unsigned int* ctr = (unsigned int*)(ws + O_CTR);

    k_transpose<<<dim3(Wn / 32, En / 32), dim3(32, 8), 0, stream>>>(w1, w1t, ctr);
    k_main<<<Bn, 512, 0, stream>>>(x, w1t, b1, gamma, beta, lin, scale, shift, ctr);
    k_out<<<Bn, 128, 0, stream>>>(lin, x, scale, shift, w2, b2, out);
}

// Round 5
// 109.374 us; speedup vs baseline: 1.3835x; 1.3835x over previous
//
#include <hip/hip_runtime.h>
#include <math.h>

#define Bn 512
#define Wn 512
#define En 512
#define EPSF 1e-5f
#define NSTAT 16   // blocks in k_statsout

typedef float fx4 __attribute__((ext_vector_type(4)));

// ---- workspace layout (float offsets) ----
#define O_W1T    0                           // En*Wn = 262144
#define O_LIN    (O_W1T + En * Wn)           // + Bn*En
#define O_PSUM   (O_LIN + Bn * En)           // + NSTAT*En
#define O_PSUMSQ (O_PSUM + NSTAT * En)       // + NSTAT*En
#define O_CTR    (O_PSUMSQ + NSTAT * En)     // + 1 (uint counter)

// W1 [E,W] -> W1T [W,E], LDS-tiled transpose. Also zeroes the spin counter
// (deterministically, every call) before k_statsout runs.
__global__ void k_transpose(const float* __restrict__ w1, float* __restrict__ w1t,
                            unsigned int* __restrict__ ctr) {
    if (blockIdx.x == 0 && blockIdx.y == 0 && threadIdx.x == 0 && threadIdx.y == 0)
        *ctr = 0u;
    __shared__ float tile[32][33];
    int bx = blockIdx.x, by = blockIdx.y;     // bx: w-tile, by: e-tile
    int tx = threadIdx.x, ty = threadIdx.y;   // (32, 8)
#pragma unroll
    for (int j = 0; j < 32; j += 8)
        tile[ty + j][tx] = w1[(size_t)(by * 32 + ty + j) * Wn + bx * 32 + tx];
    __syncthreads();
#pragma unroll
    for (int j = 0; j < 32; j += 8)
        w1t[(size_t)(bx * 32 + ty + j) * En + by * 32 + tx] = tile[tx][ty + j];
}

// EXACT R3 k_main (known-good 2 blocks/CU, ~90 us). One block per b.
// lin[b][e] = sum_w x*W1T - x_last*sumW1 + b1, sumW1 accumulated in-loop.
__global__ __launch_bounds__(512) void k_main(const float* __restrict__ x,
                                              const float* __restrict__ w1t,
                                              const float* __restrict__ b1,
                                              float* __restrict__ lin) {
    int b = blockIdx.x;
    int tid = threadIdx.x;
    int wsub = tid >> 7;      // 0..3
    int e4 = tid & 127;       // float4 index over e

    const fx4* xp = (const fx4*)x + ((size_t)b * Wn + (size_t)wsub * 128) * (En / 4) + e4;
    const fx4* wp = (const fx4*)w1t + (size_t)(wsub * 128) * (En / 4) + e4;

    fx4 acc = {0.f, 0.f, 0.f, 0.f};
    fx4 wsum = {0.f, 0.f, 0.f, 0.f};
#pragma unroll 8
    for (int w = 0; w < 128; ++w) {
        fx4 xv = __builtin_nontemporal_load(&xp[(size_t)w * (En / 4)]);
        fx4 wv = wp[(size_t)w * (En / 4)];
        acc += xv * wv;
        wsum += wv;
    }

    __shared__ fx4 lacc[4][128];
    __shared__ fx4 lws[4][128];
    lacc[wsub][e4] = acc;
    lws[wsub][e4] = wsum;
    __syncthreads();

    if (wsub == 0) {
        fx4 t = lacc[0][e4], u = lws[0][e4];
#pragma unroll
        for (int k = 1; k < 4; ++k) {
            t += lacc[k][e4];
            u += lws[k][e4];
        }
        fx4 xl = ((const fx4*)x)[((size_t)b * Wn + (Wn - 1)) * (En / 4) + e4];
        fx4 bb = ((const fx4*)b1)[e4];
        fx4 r = t - xl * u + bb;
        ((fx4*)lin)[(size_t)b * (En / 4) + e4] = r;
    }
}

// Fused BN-stats + output. NSTAT=16 blocks x 512 threads, all co-resident.
// Phase 1: per-block psum/psumsq over 32 b's. Device-scope counter barrier
// (R4-proven protocol; stale-counter replay falls through, no hang).
// Phase 2: redundant 16-way reduce -> scale/shift in LDS -> per-b dot product.
__global__ __launch_bounds__(512) void k_statsout(const float* __restrict__ lin,
                                                  const float* __restrict__ x,
                                                  const float* __restrict__ gamma,
                                                  const float* __restrict__ beta,
                                                  const float* __restrict__ w2,
                                                  const float* __restrict__ b2,
                                                  float* __restrict__ psum,
                                                  float* __restrict__ psumsq,
                                                  unsigned int* __restrict__ ctr,
                                                  float* __restrict__ out) {
    int blk = blockIdx.x;   // 0..15
    int tid = threadIdx.x;  // 0..511

    // ---- phase 1: partial stats over this block's 32 b-rows (coalesced over e)
    {
        int e = tid;
        float s = 0.f, q = 0.f;
        int b0 = blk * 32;
#pragma unroll 4
        for (int b = b0; b < b0 + 32; ++b) {
            float v = lin[(size_t)b * En + e];
            s += v;
            q += v * v;
        }
        psum[blk * En + e] = s;
        psumsq[blk * En + e] = q;
    }
    __syncthreads();
    if (tid == 0) {
        __threadfence();                       // release this block's psum writes
        atomicAdd(ctr, 1u);
        while (__hip_atomic_load(ctr, __ATOMIC_ACQUIRE, __HIP_MEMORY_SCOPE_AGENT) < NSTAT) {}
    }
    __syncthreads();
    __threadfence();                           // acquire: see all blocks' psum

    // ---- phase 2a: per-e scale/shift into LDS (redundant per block, 32 KB L2)
    __shared__ float s_sc[En];
    __shared__ float s_sh[En];
    {
        int e = tid;
        float s = 0.f, q = 0.f;
#pragma unroll
        for (int k = 0; k < NSTAT; ++k) {
            s += psum[k * En + e];
            q += psumsq[k * En + e];
        }
        float mean = s * (1.f / Bn);
        float var = q * (1.f / Bn) - mean * mean;
        float sc = gamma[e] * rsqrtf(var + EPSF);
        s_sc[e] = sc;
        s_sh[e] = beta[e] - mean * sc;
    }
    __syncthreads();

    // ---- phase 2b: out[b] for this block's 32 b's; 16 lanes per b
    {
        int bl = tid >> 4;   // 0..31 local b
        int ei = tid & 15;   // lane within b-group
        int b = blk * 32 + bl;
        const float* linb = lin + (size_t)b * En;
        const float* xlb  = x + ((size_t)b * Wn + (Wn - 1)) * En;
        float acc = 0.f;
#pragma unroll 8
        for (int j = ei; j < En; j += 16)
            acc += (linb[j] * s_sc[j] + s_sh[j] + xlb[j]) * w2[j];
#pragma unroll
        for (int off = 8; off; off >>= 1) acc += __shfl_down(acc, off, 16);
        if (ei == 0) out[b] = acc + b2[0];
    }
}

extern "C" void kernel_launch(void* const* d_in, const int* in_sizes, int n_in,
                              void* d_out, int out_size, void* d_ws, size_t ws_size,
                              hipStream_t stream) {
    const float* x     = (const float*)d_in[0];
    const float* w1    = (const float*)d_in[1];
    const float* b1    = (const float*)d_in[2];
    const float* gamma = (const float*)d_in[3];
    const float* beta  = (const float*)d_in[4];
    const float* w2    = (const float*)d_in[5];
    const float* b2    = (const float*)d_in[6];
    float* out = (float*)d_out;
    float* ws  = (float*)d_ws;

    float* w1t    = ws + O_W1T;
    float* lin    = ws + O_LIN;
    float* psum   = ws + O_PSUM;
    float* psumsq = ws + O_PSUMSQ;
    unsigned int* ctr = (unsigned int*)(ws + O_CTR);

    k_transpose<<<dim3(Wn / 32, En / 32), dim3(32, 8), 0, stream>>>(w1, w1t, ctr);
    k_main<<<Bn, 512, 0, stream>>>(x, w1t, b1, lin);
    k_statsout<<<NSTAT, 512, 0, stream>>>(lin, x, gamma, beta, w2, b2,
                                          psum, psumsq, ctr, out);
}

// Round 6
// 98.266 us; speedup vs baseline: 1.5399x; 1.1130x over previous
//
#include <hip/hip_runtime.h>
#include <math.h>

#define Bn 512
#define Wn 512
#define En 512
#define EPSF 1e-5f

typedef float fx4 __attribute__((ext_vector_type(4)));

// ---- workspace layout (float offsets) ----
#define O_W1T    0                           // En*Wn = 262144
#define O_LIN    (O_W1T + En * Wn)           // + Bn*En
#define O_PSUM   (O_LIN + Bn * En)           // + 8*En
#define O_PSUMSQ (O_PSUM + 8 * En)           // + 8*En

// W1 [E,W] -> W1T [W,E], LDS-tiled transpose
__global__ void k_transpose(const float* __restrict__ w1, float* __restrict__ w1t) {
    __shared__ float tile[32][33];
    int bx = blockIdx.x, by = blockIdx.y;     // bx: w-tile, by: e-tile
    int tx = threadIdx.x, ty = threadIdx.y;   // (32, 8)
#pragma unroll
    for (int j = 0; j < 32; j += 8)
        tile[ty + j][tx] = w1[(size_t)(by * 32 + ty + j) * Wn + bx * 32 + tx];
    __syncthreads();
#pragma unroll
    for (int j = 0; j < 32; j += 8)
        w1t[(size_t)(bx * 32 + ty + j) * En + by * 32 + tx] = tile[tx][ty + j];
}

// One block per (b, b+256) pair. 512 threads = 4 w-subchunks x 128 e4-lanes.
// One W1T load feeds TWO b-accumulators: halves W1T/L2 traffic + issue count,
// doubles per-thread memory-level parallelism on the x stream.
__global__ __launch_bounds__(512) void k_main(const float* __restrict__ x,
                                              const float* __restrict__ w1t,
                                              const float* __restrict__ b1,
                                              float* __restrict__ lin) {
    int b0 = blockIdx.x;            // handles b0 and b0+256
    int b1i = b0 + 256;
    int tid = threadIdx.x;
    int wsub = tid >> 7;            // 0..3
    int e4 = tid & 127;             // float4 index over e

    const fx4* xp0 = (const fx4*)x + ((size_t)b0  * Wn + (size_t)wsub * 128) * (En / 4) + e4;
    const fx4* xp1 = (const fx4*)x + ((size_t)b1i * Wn + (size_t)wsub * 128) * (En / 4) + e4;
    const fx4* wp  = (const fx4*)w1t + (size_t)(wsub * 128) * (En / 4) + e4;

    fx4 acc0 = {0.f, 0.f, 0.f, 0.f};
    fx4 acc1 = {0.f, 0.f, 0.f, 0.f};
    fx4 wsum = {0.f, 0.f, 0.f, 0.f};
#pragma unroll 8
    for (int w = 0; w < 128; ++w) {
        fx4 xv0 = __builtin_nontemporal_load(&xp0[(size_t)w * (En / 4)]);
        fx4 xv1 = __builtin_nontemporal_load(&xp1[(size_t)w * (En / 4)]);
        fx4 wv = wp[(size_t)w * (En / 4)];
        acc0 += xv0 * wv;
        acc1 += xv1 * wv;
        wsum += wv;
    }

    __shared__ fx4 lacc0[4][128];
    __shared__ fx4 lacc1[4][128];
    __shared__ fx4 lws[4][128];
    lacc0[wsub][e4] = acc0;
    lacc1[wsub][e4] = acc1;
    lws[wsub][e4] = wsum;
    __syncthreads();

    if (wsub == 0) {
        fx4 t0 = lacc0[0][e4], t1 = lacc1[0][e4], u = lws[0][e4];
#pragma unroll
        for (int k = 1; k < 4; ++k) {
            t0 += lacc0[k][e4];
            t1 += lacc1[k][e4];
            u  += lws[k][e4];
        }
        fx4 xl0 = ((const fx4*)x)[((size_t)b0  * Wn + (Wn - 1)) * (En / 4) + e4];
        fx4 xl1 = ((const fx4*)x)[((size_t)b1i * Wn + (Wn - 1)) * (En / 4) + e4];
        fx4 bb = ((const fx4*)b1)[e4];
        ((fx4*)lin)[(size_t)b0  * (En / 4) + e4] = t0 - xl0 * u + bb;
        ((fx4*)lin)[(size_t)b1i * (En / 4) + e4] = t1 - xl1 * u + bb;
    }
}

// per-e partial sums over 64 b's per block (coalesced over e)
__global__ void k_stats_partial(const float* __restrict__ lin,
                                float* __restrict__ psum, float* __restrict__ psumsq) {
    int blk = blockIdx.x;  // 8
    int e = threadIdx.x;   // 512
    float s = 0.f, q = 0.f;
    int b0 = blk * 64;
#pragma unroll 4
    for (int b = b0; b < b0 + 64; ++b) {
        float v = lin[(size_t)b * En + e];
        s += v;
        q += v * v;
    }
    psum[blk * En + e] = s;
    psumsq[blk * En + e] = q;
}

// out[b] = sum_e (lin*scale + shift + seq_last) * W2[e] + b2
// stats_final (8-way psum reduce -> scale/shift) inlined per block (L2-hit).
__global__ __launch_bounds__(128) void k_out(const float* __restrict__ lin,
                                             const float* __restrict__ x,
                                             const float* __restrict__ psum,
                                             const float* __restrict__ psumsq,
                                             const float* __restrict__ gamma,
                                             const float* __restrict__ beta,
                                             const float* __restrict__ w2,
                                             const float* __restrict__ b2,
                                             float* __restrict__ out) {
    int b = blockIdx.x;
    int t = threadIdx.x;  // 128 -> float4 over e

    fx4 s4 = {0.f, 0.f, 0.f, 0.f}, q4 = {0.f, 0.f, 0.f, 0.f};
#pragma unroll
    for (int c = 0; c < 8; ++c) {
        s4 += ((const fx4*)psum)[c * (En / 4) + t];
        q4 += ((const fx4*)psumsq)[c * (En / 4) + t];
    }
    fx4 g = ((const fx4*)gamma)[t];
    fx4 be = ((const fx4*)beta)[t];
    fx4 mean = s4 * (1.f / Bn);
    fx4 var = q4 * (1.f / Bn) - mean * mean;
    fx4 sc, sh;
    sc.x = g.x * rsqrtf(var.x + EPSF); sc.y = g.y * rsqrtf(var.y + EPSF);
    sc.z = g.z * rsqrtf(var.z + EPSF); sc.w = g.w * rsqrtf(var.w + EPSF);
    sh = be - mean * sc;

    fx4 l  = ((const fx4*)lin)[(size_t)b * (En / 4) + t];
    fx4 xl = ((const fx4*)x)[((size_t)b * Wn + (Wn - 1)) * (En / 4) + t];
    fx4 wv = ((const fx4*)w2)[t];
    fx4 term = (l * sc + sh + xl) * wv;
    float v = term.x + term.y + term.z + term.w;
#pragma unroll
    for (int off = 32; off; off >>= 1) v += __shfl_down(v, off);
    __shared__ float red[2];
    int wid = t >> 6, lane = t & 63;
    if (lane == 0) red[wid] = v;
    __syncthreads();
    if (t == 0) out[b] = red[0] + red[1] + b2[0];
}

extern "C" void kernel_launch(void* const* d_in, const int* in_sizes, int n_in,
                              void* d_out, int out_size, void* d_ws, size_t ws_size,
                              hipStream_t stream) {
    const float* x     = (const float*)d_in[0];
    const float* w1    = (const float*)d_in[1];
    const float* b1    = (const float*)d_in[2];
    const float* gamma = (const float*)d_in[3];
    const float* beta  = (const float*)d_in[4];
    const float* w2    = (const float*)d_in[5];
    const float* b2    = (const float*)d_in[6];
    float* out = (float*)d_out;
    float* ws  = (float*)d_ws;

    float* w1t    = ws + O_W1T;
    float* lin    = ws + O_LIN;
    float* psum   = ws + O_PSUM;
    float* psumsq = ws + O_PSUMSQ;

    k_transpose<<<dim3(Wn / 32, En / 32), dim3(32, 8), 0, stream>>>(w1, w1t);
    k_main<<<Bn / 2, 512, 0, stream>>>(x, w1t, b1, lin);
    k_stats_partial<<<8, 512, 0, stream>>>(lin, psum, psumsq);
    k_out<<<Bn, 128, 0, stream>>>(lin, x, psum, psumsq, gamma, beta, w2, b2, out);
}